// Round 3
// baseline (204.145 us; speedup 1.0000x reference)
//
#include <hip/hip_runtime.h>
#include <hip/hip_bf16.h>
#include <math.h>

// (B, Cin, Cout, N, modes) = (16, 128, 128, 8192, 64)
#define NB    16
#define NCIN  128
#define NCOUT 128
#define NN    8192
#define NMOD  64

typedef short bf16x8 __attribute__((ext_vector_type(8)));   // 8 bf16 = 4 VGPRs
typedef float f32x4  __attribute__((ext_vector_type(4)));   // MFMA acc

#define MFMA16(a, b, c) __builtin_amdgcn_mfma_f32_16x16x32_bf16((a), (b), (c), 0, 0, 0)

__device__ inline unsigned short f2bf_rne(float f) {        // round-to-nearest-even
    unsigned u = __float_as_uint(f);
    u += 0x7FFF + ((u >> 16) & 1);
    return (unsigned short)(u >> 16);
}
__device__ inline short f2bf_trunc(float f) {               // cheap truncation (hot path)
    return (short)(__float_as_uint(f) >> 16);
}

// ---- prep: trig tables, bf16 conv weight, packed spectral weights -----------
// T  [128][8192]: T[2k][n]=cos, T[2k+1][n]=-sin            (fwd-DFT B-op)
// Tt [8192][128]: Tt[n][m]=T[m][n]                         (synthesis B-op)
// Wpk[k][h][o][kk=256] bf16: h=0 re-mix, h=1 im-mix; scale 2/N (1/N, im=0 at k=0)
__global__ __launch_bounds__(256) void k_prep(const float* __restrict__ wc,
                                              const float* __restrict__ wsp,
                                              unsigned short* __restrict__ T,
                                              unsigned short* __restrict__ Tt,
                                              unsigned short* __restrict__ Wcb,
                                              unsigned short* __restrict__ Wpk) {
    const float C = 7.66990393943e-4f; // 2*pi/8192
    if (blockIdx.x < 16) {                         // region A: T rows
        int a = blockIdx.x * 256 + threadIdx.x;
        int k = a >> 6, n0 = (a & 63) * 128;
        for (int j8 = 0; j8 < 16; ++j8) {
            short c8[8], s8[8];
            #pragma unroll
            for (int j = 0; j < 8; ++j) {
                int n = n0 + j8 * 8 + j;
                int ph = (k * n) & (NN - 1);
                float sn, cs; __sincosf((float)ph * C, &sn, &cs);
                c8[j] = (short)f2bf_rne(cs);
                s8[j] = (short)f2bf_rne(-sn);
            }
            *(bf16x8*)(T + (size_t)(2 * k) * NN + n0 + j8 * 8)     = *(bf16x8*)c8;
            *(bf16x8*)(T + (size_t)(2 * k + 1) * NN + n0 + j8 * 8) = *(bf16x8*)s8;
        }
    } else if (blockIdx.x < 48) {                  // region B: Tt rows
        int n = (blockIdx.x - 16) * 256 + threadIdx.x;
        for (int k4 = 0; k4 < 16; ++k4) {
            short buf[8];
            #pragma unroll
            for (int j = 0; j < 4; ++j) {
                int k = k4 * 4 + j;
                int ph = (n * k) & (NN - 1);
                float sn, cs; __sincosf((float)ph * C, &sn, &cs);
                buf[2 * j]     = (short)f2bf_rne(cs);
                buf[2 * j + 1] = (short)f2bf_rne(-sn);
            }
            *(bf16x8*)(Tt + (size_t)n * 128 + k4 * 8) = *(bf16x8*)buf;
        }
    } else if (blockIdx.x < 112) {                 // region C: Wc -> bf16
        int j = (blockIdx.x - 48) * 256 + threadIdx.x;
        if (j < NCOUT * NCIN) Wcb[j] = f2bf_rne(wc[j]);
    } else {                                       // region D: pack Wpk
        int g2 = (blockIdx.x - 112) * 256 + threadIdx.x;   // 0..32767
        int k  = g2 & 63;
        int o  = (g2 >> 6) & 127;
        int ch = g2 >> 13;                                  // 0..3
        const float s = (k == 0) ? (1.f / NN) : (2.f / NN);
        const float2* wp = (const float2*)wsp;              // [(i*128+o)*64 + k]
        unsigned short* wre = Wpk + ((size_t)(k * 2 + 0) * 128 + o) * 256;
        unsigned short* wim = Wpk + ((size_t)(k * 2 + 1) * 128 + o) * 256;
        for (int c = ch * 8; c < ch * 8 + 8; ++c) {
            int i0 = 4 * c;
            short re8[8], im8[8];
            #pragma unroll
            for (int t2 = 0; t2 < 4; ++t2) {
                float2 wv = wp[((size_t)(i0 + t2) * 128 + o) * 64 + k];  // lanes: k-contig
                float wr = s * wv.x, wi = s * wv.y;
                re8[2 * t2]     = (short)f2bf_rne(wr);
                re8[2 * t2 + 1] = (short)f2bf_rne(-wi);
                im8[2 * t2]     = (k == 0) ? (short)0 : (short)f2bf_rne(wi);
                im8[2 * t2 + 1] = (k == 0) ? (short)0 : (short)f2bf_rne(wr);
            }
            *(bf16x8*)(wre + c * 8) = *(bf16x8*)re8;   // per-lane sequential -> L2 merges
            *(bf16x8*)(wim + c * 8) = *(bf16x8*)im8;
        }
    }
}

// ---- GEMM1: Cpart[sp][row][col] = (x * T^T) K-split partials ----------------
// Reg-staged 2-phase pipeline (unchanged). Store layout flipped to [row][col]:
// scalar stores, lanes col-contiguous -> 4x64B segments/instr (was 16-line
// scatter at 8KB col-stride).
__global__ __launch_bounds__(256) void k_dftmm(const float* __restrict__ x,
                                               const unsigned short* __restrict__ T,
                                               float* __restrict__ Cpart) {
    const int mt = blockIdx.x & 63, sp = blockIdx.x >> 6;
    const int w = threadIdx.x >> 6, l = threadIdx.x & 63;
    const int l15 = l & 15, q = l >> 4;
    const int colbase = w * 32;
    __shared__ short As[8192];                 // 2 bufs x [32 rows][128 k] bf16, swizzled

    // staging assignment: thread -> (row sr, 16-float group sc)
    const int sr = threadIdx.x >> 3;           // 0..31
    const int sc = threadIdx.x & 7;            // 0..7  (floats sc*16 .. sc*16+15)
    const float* xrow = x + (size_t)(mt * 32 + sr) * NN + sp * 512 + sc * 16;
    short* wp0 = As + sr * 128 + (((sc * 2    ) ^ (sr & 7)) * 8);
    short* wp1 = As + sr * 128 + (((sc * 2 + 1) ^ (sr & 7)) * 8);

    float4 ra, rb, rc, rd;
#define LOADC(c) { const float* p_ = xrow + (c) * 128;                         \
        ra = *(const float4*)p_;       rb = *(const float4*)(p_ + 4);          \
        rc = *(const float4*)(p_ + 8); rd = *(const float4*)(p_ + 12); }
#define WRITEC(bufi) {                                                          \
        short t0_[8] = { f2bf_trunc(ra.x), f2bf_trunc(ra.y), f2bf_trunc(ra.z), f2bf_trunc(ra.w), \
                         f2bf_trunc(rb.x), f2bf_trunc(rb.y), f2bf_trunc(rb.z), f2bf_trunc(rb.w) }; \
        short t1_[8] = { f2bf_trunc(rc.x), f2bf_trunc(rc.y), f2bf_trunc(rc.z), f2bf_trunc(rc.w), \
                         f2bf_trunc(rd.x), f2bf_trunc(rd.y), f2bf_trunc(rd.z), f2bf_trunc(rd.w) }; \
        *(bf16x8*)(wp0 + (bufi) * 4096) = *(bf16x8*)t0_;                        \
        *(bf16x8*)(wp1 + (bufi) * 4096) = *(bf16x8*)t1_; }

    // B-operand bases (direct global; T slice is L2-resident across mt blocks)
    const unsigned short* Tp0 = T + (size_t)(colbase + l15) * NN + sp * 512 + q * 8;
    const unsigned short* Tp1 = Tp0 + (size_t)16 * NN;

    // A-frag read addresses (swizzle-matched): row r, chunk c=kk*4+q, c^=(r&7)
    const int rsw = l15 & 7;

    LOADC(0);
    WRITEC(0);
    __syncthreads();

    f32x4 acc[2][2] = {};
    int buf = 0;
    for (int c = 0; c < 4; ++c) {
        if (c < 3) LOADC(c + 1);               // issue next-chunk loads early
        const short* Ab = As + buf * 4096;
        #pragma unroll
        for (int kk = 0; kk < 4; ++kk) {
            int ce = ((kk * 4 + q) ^ rsw) * 8;
            bf16x8 a0 = *(const bf16x8*)(Ab + l15 * 128 + ce);
            bf16x8 a1 = *(const bf16x8*)(Ab + (16 + l15) * 128 + ce);
            bf16x8 b0 = *(const bf16x8*)(Tp0 + c * 128 + kk * 32);
            bf16x8 b1 = *(const bf16x8*)(Tp1 + c * 128 + kk * 32);
            acc[0][0] = MFMA16(a0, b0, acc[0][0]);
            acc[0][1] = MFMA16(a0, b1, acc[0][1]);
            acc[1][0] = MFMA16(a1, b0, acc[1][0]);
            acc[1][1] = MFMA16(a1, b1, acc[1][1]);
        }
        if (c < 3) {
            WRITEC(buf ^ 1);                   // cvt + LDS write after compute
            __syncthreads();
            buf ^= 1;
        }
    }
#undef LOADC
#undef WRITEC

    #pragma unroll
    for (int mf = 0; mf < 2; ++mf)
        #pragma unroll
        for (int nf = 0; nf < 2; ++nf) {
            int col = colbase + nf * 16 + l15;
            #pragma unroll
            for (int r = 0; r < 4; ++r) {
                int row = mt * 32 + mf * 16 + q * 4 + r;
                Cpart[(size_t)sp * 262144 + (size_t)row * 128 + col] = acc[mf][nf][r];
            }
        }
}

// ---- reduce 16 K-split partials + cvt + permute -> Axh[k][b][2i+p] bf16 -----
// Axh is exactly k_mixmm's A-fragment layout (kk = 2i+p interleave). The 2B
// scattered writes are absorbed by L2 (Axh = 512 KB, resident).
__global__ __launch_bounds__(256) void k_reduce(const float* __restrict__ Cpart,
                                                unsigned short* __restrict__ Axh) {
    int t = blockIdx.x * 256 + threadIdx.x;   // t = row*128 + col, 262144
    float s = 0.f;
    #pragma unroll
    for (int sp = 0; sp < 16; ++sp) s += Cpart[(size_t)sp * 262144 + t];
    int col = t & 127, row = t >> 7;
    int k = col >> 1, p = col & 1;            // col = 2k + p
    int b = row >> 7, i = row & 127;          // row = b*128 + i
    Axh[((size_t)k * 16 + b) * 256 + i * 2 + p] = f2bf_rne(s);
}

// ---- mix: MFMA complex channel mix -> Aspec[b][o][kk=2k+p] bf16 -------------
// grid 512 blocks x 1 wave: block = (k, o-sixteenth). A-loads now per-lane
// contiguous bf16x8 from Axh (no cvt, half the bytes of the old f32 path).
__global__ __launch_bounds__(64) void k_mixmm(const unsigned short* __restrict__ Axh,
                                              const unsigned short* __restrict__ Wpk,
                                              unsigned short* __restrict__ Aspec) {
    const int k = blockIdx.x >> 3, oq = blockIdx.x & 7;
    const int l = threadIdx.x, l15 = l & 15, q = l >> 4;
    f32x4 ar = {}, ai = {};
    const unsigned short* Ab = Axh + ((size_t)k * 16 + l15) * 256;   // lane = b
    const int o = oq * 16 + l15;
    #pragma unroll
    for (int kt = 0; kt < 8; ++kt) {
        bf16x8 a = *(const bf16x8*)(Ab + kt * 32 + q * 8);
        const unsigned short* wb = Wpk + ((size_t)(k * 2) * 128 + o) * 256 + kt * 32 + q * 8;
        bf16x8 bre = *(const bf16x8*)wb;
        bf16x8 bim = *(const bf16x8*)(wb + 32768);   // h-stride 128*256
        ar = MFMA16(a, bre, ar);
        ai = MFMA16(a, bim, ai);
    }
    #pragma unroll
    for (int r = 0; r < 4; ++r) {
        int b = q * 4 + r;
        unsigned v = (unsigned)f2bf_rne(ar[r]) | ((unsigned)f2bf_rne(ai[r]) << 16);
        *(unsigned*)(Aspec + ((size_t)b * 128 + o) * 128 + 2 * k) = v;
    }
}

// ---- GEMM3: out = [Aspec_b | Wcb] x [Tt^T ; x_b] + bias, GELU ---------------
// n-tile 32 -> 4096 blocks (16 b x 256 nt), 4 waves each own an o-quarter x
// full n-tile, acc[2][2]=16 regs. Per-thread global loads 48 -> 28.
__global__ __launch_bounds__(256) void k_out(const float* __restrict__ x,
                                             const unsigned short* __restrict__ Tt,
                                             const unsigned short* __restrict__ Aspec,
                                             const unsigned short* __restrict__ Wcb,
                                             const float* __restrict__ bias,
                                             float* __restrict__ out) {
    const int b = blockIdx.x >> 8, nt = blockIdx.x & 255;
    const int w = threadIdx.x >> 6, l = threadIdx.x & 63;
    const int l15 = l & 15, q = l >> 4;
    __shared__ short xs[4096];   // 8 KB: logical [n=32][i=128], XOR-swizzled 16B chunks

    // ---- stage x-tile: fp32 coalesced reads -> bf16 pairs, transposed writes
    const float* xb = x + (size_t)b * 128 * NN + nt * 32;
    #pragma unroll
    for (int it = 0; it < 2; ++it) {
        int unit = it * 256 + threadIdx.x;       // 512 units
        int ipair = unit >> 3, nq = unit & 7;
        int i0 = ipair * 2;
        const float* p0 = xb + (size_t)i0 * NN + nq * 4;
        float4 r0 = *(const float4*)p0;
        float4 r1 = *(const float4*)(p0 + NN);
        float a0[4] = { r0.x, r0.y, r0.z, r0.w };
        float a1[4] = { r1.x, r1.y, r1.z, r1.w };
        #pragma unroll
        for (int j = 0; j < 4; ++j) {
            int n = nq * 4 + j;
            unsigned v = (unsigned)(unsigned short)f2bf_trunc(a0[j])
                       | ((unsigned)(unsigned short)f2bf_trunc(a1[j]) << 16);
            int swz = (n ^ (n >> 2)) & 15;
            int addr = n * 128 + (((i0 >> 3) ^ swz) * 8) + (i0 & 7);
            *(unsigned*)&xs[addr] = v;
        }
    }

    const int obase = w * 32;
    const int nbase = nt * 32;
    f32x4 acc[2][2] = {};
    // ---- spectral half first (no LDS dependency -> staging drains for free)
    #pragma unroll
    for (int kt = 0; kt < 4; ++kt) {
        bf16x8 bb[2];
        #pragma unroll
        for (int nf = 0; nf < 2; ++nf) {
            int n = nbase + nf * 16 + l15;
            bb[nf] = *(const bf16x8*)(Tt + (size_t)n * 128 + kt * 32 + q * 8);
        }
        const unsigned short* Ap = Aspec + (size_t)b * 16384 + kt * 32 + q * 8;
        #pragma unroll
        for (int mf = 0; mf < 2; ++mf) {
            bf16x8 a = *(const bf16x8*)(Ap + (size_t)(obase + mf * 16 + l15) * 128);
            acc[mf][0] = MFMA16(a, bb[0], acc[mf][0]);
            acc[mf][1] = MFMA16(a, bb[1], acc[mf][1]);
        }
    }
    __syncthreads();
    // ---- conv half: B from LDS (ds_read_b128, swizzle-matched)
    #pragma unroll
    for (int kt = 0; kt < 4; ++kt) {
        bf16x8 bb[2];
        #pragma unroll
        for (int nf = 0; nf < 2; ++nf) {
            int nl = nf * 16 + l15;
            int c  = kt * 4 + q;
            int swz = (nl ^ (nl >> 2)) & 15;
            bb[nf] = *(const bf16x8*)&xs[nl * 128 + ((c ^ swz) * 8)];
        }
        const unsigned short* Ap = Wcb + kt * 32 + q * 8;
        #pragma unroll
        for (int mf = 0; mf < 2; ++mf) {
            bf16x8 a = *(const bf16x8*)(Ap + (size_t)(obase + mf * 16 + l15) * 128);
            acc[mf][0] = MFMA16(a, bb[0], acc[mf][0]);
            acc[mf][1] = MFMA16(a, bb[1], acc[mf][1]);
        }
    }
    // ---- epilogue: bias + fast GELU
    #pragma unroll
    for (int mf = 0; mf < 2; ++mf)
        #pragma unroll
        for (int nf = 0; nf < 2; ++nf)
            #pragma unroll
            for (int r = 0; r < 4; ++r) {
                int o = obase + mf * 16 + q * 4 + r;
                int n = nbase + nf * 16 + l15;
                float v = acc[mf][nf][r] + bias[o];
                float u = v * v;
                float p = v * fmaf(0.0713548162f, u, 1.5957691216f);
                float e = __expf(-p);
                float g = v * __builtin_amdgcn_rcpf(1.f + e);
                out[((size_t)(b * 128 + o)) * NN + n] = g;
            }
}

extern "C" void kernel_launch(void* const* d_in, const int* in_sizes, int n_in,
                              void* d_out, int out_size, void* d_ws, size_t ws_size,
                              hipStream_t stream) {
    const float* x    = (const float*)d_in[0];  // [16][128][8192]
    const float* wsp  = (const float*)d_in[1];  // [128][128][64][2]
    const float* wc   = (const float*)d_in[2];  // [128][128]
    const float* bc   = (const float*)d_in[3];  // [128]
    float* out = (float*)d_out;

    unsigned short* T   = (unsigned short*)d_ws;            // 2 MB
    unsigned short* Tt  = T + (size_t)1048576;              // 2 MB
    unsigned short* Wcb = Tt + (size_t)1048576;             // 32 KB
    unsigned short* Asp = Wcb + 16384;                      // 512 KB
    unsigned short* Wpk = Asp + 262144;                     // 16.8 MB
    float* Cpart = (float*)(Wpk + (size_t)8388608);         // 16 MB
    unsigned short* Axh = (unsigned short*)(Cpart + (size_t)16 * 262144);  // 512 KB

    k_prep  <<<240,  256, 0, stream>>>(wc, wsp, T, Tt, Wcb, Wpk);
    k_dftmm <<<1024, 256, 0, stream>>>(x, T, Cpart);
    k_reduce<<<1024, 256, 0, stream>>>(Cpart, Axh);
    k_mixmm <<<512,  64,  0, stream>>>(Axh, Wpk, Asp);
    k_out   <<<4096, 256, 0, stream>>>(x, Tt, Asp, Wcb, bc, out);
}

// Round 4
// 191.383 us; speedup vs baseline: 1.0667x; 1.0667x over previous
//
#include <hip/hip_runtime.h>
#include <hip/hip_bf16.h>
#include <math.h>

// (B, Cin, Cout, N, modes) = (16, 128, 128, 8192, 64)
#define NB    16
#define NCIN  128
#define NCOUT 128
#define NN    8192
#define NMOD  64

typedef short bf16x8 __attribute__((ext_vector_type(8)));   // 8 bf16 = 4 VGPRs
typedef float f32x4  __attribute__((ext_vector_type(4)));   // MFMA acc

#define MFMA16(a, b, c) __builtin_amdgcn_mfma_f32_16x16x32_bf16((a), (b), (c), 0, 0, 0)

__device__ inline unsigned short f2bf_rne(float f) {        // round-to-nearest-even
    unsigned u = __float_as_uint(f);
    u += 0x7FFF + ((u >> 16) & 1);
    return (unsigned short)(u >> 16);
}
__device__ inline short f2bf_trunc(float f) {               // cheap truncation (hot path)
    return (short)(__float_as_uint(f) >> 16);
}

// ---- prep: trig tables, bf16 conv weight, packed spectral weights -----------
// T  [128][8192]: T[2k][n]=cos, T[2k+1][n]=-sin            (fwd-DFT B-op)
// Tt [8192][128]: Tt[n][m]=T[m][n]                         (synthesis B-op)
// Wpk[k][h][o][kk=256] bf16: h=0 re-mix, h=1 im-mix; scale 2/N (1/N, im=0 at k=0)
// Region D rewritten: one block per o, coalesced wsp reads (k innermost ->
// 256B contiguous per thread) staged in 64KB LDS, packed bf16x8 writes.
__global__ __launch_bounds__(256) void k_prep(const float* __restrict__ wc,
                                              const float* __restrict__ wsp,
                                              unsigned short* __restrict__ T,
                                              unsigned short* __restrict__ Tt,
                                              unsigned short* __restrict__ Wcb,
                                              unsigned short* __restrict__ Wpk) {
    const float C = 7.66990393943e-4f; // 2*pi/8192
    if (blockIdx.x < 16) {                         // region A: T rows
        int a = blockIdx.x * 256 + threadIdx.x;
        int k = a >> 6, n0 = (a & 63) * 128;
        for (int j8 = 0; j8 < 16; ++j8) {
            short c8[8], s8[8];
            #pragma unroll
            for (int j = 0; j < 8; ++j) {
                int n = n0 + j8 * 8 + j;
                int ph = (k * n) & (NN - 1);
                float sn, cs; __sincosf((float)ph * C, &sn, &cs);
                c8[j] = (short)f2bf_rne(cs);
                s8[j] = (short)f2bf_rne(-sn);
            }
            *(bf16x8*)(T + (size_t)(2 * k) * NN + n0 + j8 * 8)     = *(bf16x8*)c8;
            *(bf16x8*)(T + (size_t)(2 * k + 1) * NN + n0 + j8 * 8) = *(bf16x8*)s8;
        }
    } else if (blockIdx.x < 48) {                  // region B: Tt rows
        int n = (blockIdx.x - 16) * 256 + threadIdx.x;
        for (int k4 = 0; k4 < 16; ++k4) {
            short buf[8];
            #pragma unroll
            for (int j = 0; j < 4; ++j) {
                int k = k4 * 4 + j;
                int ph = (n * k) & (NN - 1);
                float sn, cs; __sincosf((float)ph * C, &sn, &cs);
                buf[2 * j]     = (short)f2bf_rne(cs);
                buf[2 * j + 1] = (short)f2bf_rne(-sn);
            }
            *(bf16x8*)(Tt + (size_t)n * 128 + k4 * 8) = *(bf16x8*)buf;
        }
    } else if (blockIdx.x < 112) {                 // region C: Wc -> bf16
        int j = (blockIdx.x - 48) * 256 + threadIdx.x;
        if (j < NCOUT * NCIN) Wcb[j] = f2bf_rne(wc[j]);
    } else {                                       // region D: pack Wpk (block = o)
        int o = blockIdx.x - 112;                  // 0..127
        __shared__ float2 wl[8192];                // [i=128][k=64] = 64 KB
        {
            int i = threadIdx.x >> 1, h2 = threadIdx.x & 1;   // 32 float2 per thread
            const float2* src = (const float2*)wsp + (size_t)(i * 128 + o) * 64 + h2 * 32;
            float2* dst = wl + i * 64 + h2 * 32;
            #pragma unroll
            for (int j = 0; j < 32; j += 4) {      // 256B contiguous stream per thread
                float4 v0 = *(const float4*)(src + j);
                float4 v1 = *(const float4*)(src + j + 2);
                *(float4*)(dst + j)     = v0;
                *(float4*)(dst + j + 2) = v1;
            }
        }
        __syncthreads();
        int k = threadIdx.x >> 2, qc = threadIdx.x & 3;       // kk-quarter qc*64..+64
        const float s = (k == 0) ? (1.f / NN) : (2.f / NN);
        unsigned short* wre = Wpk + ((size_t)(k * 2 + 0) * 128 + o) * 256 + qc * 64;
        unsigned short* wim = wre + 32768;                    // h-stride 128*256
        #pragma unroll
        for (int c8 = 0; c8 < 4; ++c8) {           // 8 i (=16 kk) per chunk
            short re16[16], im16[16];
            #pragma unroll
            for (int t = 0; t < 8; ++t) {
                int i = qc * 32 + c8 * 8 + t;
                float2 wv = wl[i * 64 + k];
                float wr = s * wv.x, wi = s * wv.y;
                re16[2 * t]     = (short)f2bf_rne(wr);
                re16[2 * t + 1] = (short)f2bf_rne(-wi);
                im16[2 * t]     = (k == 0) ? (short)0 : (short)f2bf_rne(wi);
                im16[2 * t + 1] = (k == 0) ? (short)0 : (short)f2bf_rne(wr);
            }
            *(bf16x8*)(wre + c8 * 16)     = *(bf16x8*)re16;
            *(bf16x8*)(wre + c8 * 16 + 8) = *(bf16x8*)(re16 + 8);
            *(bf16x8*)(wim + c8 * 16)     = *(bf16x8*)im16;
            *(bf16x8*)(wim + c8 * 16 + 8) = *(bf16x8*)(im16 + 8);
        }
    }
}

// ---- GEMM1: Cpart[sp][col][row] = (x * T^T) K-split partials ----------------
// Reg-staged 2-phase pipeline; f32x4 stores ([col][row]: q-lanes fill 64B
// lines, line-complete — measured round-2 form).
__global__ __launch_bounds__(256) void k_dftmm(const float* __restrict__ x,
                                               const unsigned short* __restrict__ T,
                                               float* __restrict__ Cpart) {
    const int mt = blockIdx.x & 63, sp = blockIdx.x >> 6;
    const int w = threadIdx.x >> 6, l = threadIdx.x & 63;
    const int l15 = l & 15, q = l >> 4;
    const int colbase = w * 32;
    __shared__ short As[8192];                 // 2 bufs x [32 rows][128 k] bf16, swizzled

    // staging assignment: thread -> (row sr, 16-float group sc)
    const int sr = threadIdx.x >> 3;           // 0..31
    const int sc = threadIdx.x & 7;            // 0..7  (floats sc*16 .. sc*16+15)
    const float* xrow = x + (size_t)(mt * 32 + sr) * NN + sp * 512 + sc * 16;
    short* wp0 = As + sr * 128 + (((sc * 2    ) ^ (sr & 7)) * 8);
    short* wp1 = As + sr * 128 + (((sc * 2 + 1) ^ (sr & 7)) * 8);

    float4 ra, rb, rc, rd;
#define LOADC(c) { const float* p_ = xrow + (c) * 128;                         \
        ra = *(const float4*)p_;       rb = *(const float4*)(p_ + 4);          \
        rc = *(const float4*)(p_ + 8); rd = *(const float4*)(p_ + 12); }
#define WRITEC(bufi) {                                                          \
        short t0_[8] = { f2bf_trunc(ra.x), f2bf_trunc(ra.y), f2bf_trunc(ra.z), f2bf_trunc(ra.w), \
                         f2bf_trunc(rb.x), f2bf_trunc(rb.y), f2bf_trunc(rb.z), f2bf_trunc(rb.w) }; \
        short t1_[8] = { f2bf_trunc(rc.x), f2bf_trunc(rc.y), f2bf_trunc(rc.z), f2bf_trunc(rc.w), \
                         f2bf_trunc(rd.x), f2bf_trunc(rd.y), f2bf_trunc(rd.z), f2bf_trunc(rd.w) }; \
        *(bf16x8*)(wp0 + (bufi) * 4096) = *(bf16x8*)t0_;                        \
        *(bf16x8*)(wp1 + (bufi) * 4096) = *(bf16x8*)t1_; }

    // B-operand bases (direct global; T slice is L2-resident across mt blocks)
    const unsigned short* Tp0 = T + (size_t)(colbase + l15) * NN + sp * 512 + q * 8;
    const unsigned short* Tp1 = Tp0 + (size_t)16 * NN;

    // A-frag read addresses (swizzle-matched): row r, chunk c=kk*4+q, c^=(r&7)
    const int rsw = l15 & 7;

    LOADC(0);
    WRITEC(0);
    __syncthreads();

    f32x4 acc[2][2] = {};
    int buf = 0;
    for (int c = 0; c < 4; ++c) {
        if (c < 3) LOADC(c + 1);               // issue next-chunk loads early
        const short* Ab = As + buf * 4096;
        #pragma unroll
        for (int kk = 0; kk < 4; ++kk) {
            int ce = ((kk * 4 + q) ^ rsw) * 8;
            bf16x8 a0 = *(const bf16x8*)(Ab + l15 * 128 + ce);
            bf16x8 a1 = *(const bf16x8*)(Ab + (16 + l15) * 128 + ce);
            bf16x8 b0 = *(const bf16x8*)(Tp0 + c * 128 + kk * 32);
            bf16x8 b1 = *(const bf16x8*)(Tp1 + c * 128 + kk * 32);
            acc[0][0] = MFMA16(a0, b0, acc[0][0]);
            acc[0][1] = MFMA16(a0, b1, acc[0][1]);
            acc[1][0] = MFMA16(a1, b0, acc[1][0]);
            acc[1][1] = MFMA16(a1, b1, acc[1][1]);
        }
        if (c < 3) {
            WRITEC(buf ^ 1);                   // cvt + LDS write after compute
            __syncthreads();
            buf ^= 1;
        }
    }
#undef LOADC
#undef WRITEC

    #pragma unroll
    for (int mf = 0; mf < 2; ++mf)
        #pragma unroll
        for (int nf = 0; nf < 2; ++nf) {
            int col  = colbase + nf * 16 + l15;
            int row0 = mt * 32 + mf * 16 + q * 4;
            *(f32x4*)(Cpart + (size_t)sp * 262144 + (size_t)col * 2048 + row0) = acc[mf][nf];
        }
}

// ---- reduce 16 K-split partials + cvt + permute -> Axh[k][b][2i+p] bf16 -----
// Axh is exactly k_mixmm's A-fragment layout. 2B scattered writes absorbed
// by L2 (Axh = 512 KB, resident). Decode: t = col*2048 + row ([col][row]).
__global__ __launch_bounds__(256) void k_reduce(const float* __restrict__ Cpart,
                                                unsigned short* __restrict__ Axh) {
    int t = blockIdx.x * 256 + threadIdx.x;   // 262144
    float s = 0.f;
    #pragma unroll
    for (int sp = 0; sp < 16; ++sp) s += Cpart[(size_t)sp * 262144 + t];
    int col = t >> 11, row = t & 2047;
    int k = col >> 1, p = col & 1;            // col = 2k + p
    int b = row >> 7, i = row & 127;          // row = b*128 + i
    Axh[((size_t)k * 16 + b) * 256 + i * 2 + p] = f2bf_rne(s);
}

// ---- mix: MFMA complex channel mix -> Aspec[b][o][kk=2k+p] bf16 -------------
// grid 512 blocks x 1 wave: block = (k, o-sixteenth). A-loads per-lane
// contiguous bf16x8 from Axh (no cvt).
__global__ __launch_bounds__(64) void k_mixmm(const unsigned short* __restrict__ Axh,
                                              const unsigned short* __restrict__ Wpk,
                                              unsigned short* __restrict__ Aspec) {
    const int k = blockIdx.x >> 3, oq = blockIdx.x & 7;
    const int l = threadIdx.x, l15 = l & 15, q = l >> 4;
    f32x4 ar = {}, ai = {};
    const unsigned short* Ab = Axh + ((size_t)k * 16 + l15) * 256;   // lane = b
    const int o = oq * 16 + l15;
    #pragma unroll
    for (int kt = 0; kt < 8; ++kt) {
        bf16x8 a = *(const bf16x8*)(Ab + kt * 32 + q * 8);
        const unsigned short* wb = Wpk + ((size_t)(k * 2) * 128 + o) * 256 + kt * 32 + q * 8;
        bf16x8 bre = *(const bf16x8*)wb;
        bf16x8 bim = *(const bf16x8*)(wb + 32768);   // h-stride 128*256
        ar = MFMA16(a, bre, ar);
        ai = MFMA16(a, bim, ai);
    }
    #pragma unroll
    for (int r = 0; r < 4; ++r) {
        int b = q * 4 + r;
        unsigned v = (unsigned)f2bf_rne(ar[r]) | ((unsigned)f2bf_rne(ai[r]) << 16);
        *(unsigned*)(Aspec + ((size_t)b * 128 + o) * 128 + 2 * k) = v;
    }
}

// ---- GEMM3: out = [Aspec_b | Wcb] x [Tt^T ; x_b] + bias, GELU ---------------
// Round-2 geometry (measured 51 us): n-tile 64 -> 2048 blocks (16 b x 128 nt),
// 4 waves = 2 o-halves x 2 n-halves, acc[4][2]=32 regs/thread.
// n32 regressed (A-operand replication doubles L2 traffic per output).
__global__ __launch_bounds__(256) void k_out(const float* __restrict__ x,
                                             const unsigned short* __restrict__ Tt,
                                             const unsigned short* __restrict__ Aspec,
                                             const unsigned short* __restrict__ Wcb,
                                             const float* __restrict__ bias,
                                             float* __restrict__ out) {
    const int b = blockIdx.x >> 7, nt = blockIdx.x & 127;
    const int w = threadIdx.x >> 6, l = threadIdx.x & 63;
    const int l15 = l & 15, q = l >> 4;
    const int wo = w >> 1, wn = w & 1;
    __shared__ short xs[8192];   // 16 KB: logical [n=64][i=128], XOR-swizzled 16B chunks

    // ---- stage x-tile: fp32 coalesced reads -> bf16 pairs, transposed writes
    const float* xb = x + (size_t)b * 128 * NN + nt * 64;
    #pragma unroll
    for (int it = 0; it < 4; ++it) {
        int unit = it * 256 + threadIdx.x;       // 1024 units
        int ipair = unit >> 4, nq = unit & 15;
        int i0 = ipair * 2;
        const float* p0 = xb + (size_t)i0 * NN + nq * 4;
        float4 r0 = *(const float4*)p0;
        float4 r1 = *(const float4*)(p0 + NN);
        float a0[4] = { r0.x, r0.y, r0.z, r0.w };
        float a1[4] = { r1.x, r1.y, r1.z, r1.w };
        #pragma unroll
        for (int j = 0; j < 4; ++j) {
            int n = nq * 4 + j;
            unsigned v = (unsigned)(unsigned short)f2bf_trunc(a0[j])
                       | ((unsigned)(unsigned short)f2bf_trunc(a1[j]) << 16);
            int swz = (n ^ (n >> 2)) & 15;
            int addr = n * 128 + (((i0 >> 3) ^ swz) * 8) + (i0 & 7);
            *(unsigned*)&xs[addr] = v;
        }
    }

    const int obase = wo * 64;
    const int nbase = nt * 64 + wn * 32;
    f32x4 acc[4][2] = {};
    // ---- spectral half first (no LDS dependency -> staging drains for free)
    #pragma unroll
    for (int kt = 0; kt < 4; ++kt) {
        bf16x8 bb[2];
        #pragma unroll
        for (int nf = 0; nf < 2; ++nf) {
            int n = nbase + nf * 16 + l15;
            bb[nf] = *(const bf16x8*)(Tt + (size_t)n * 128 + kt * 32 + q * 8);
        }
        const unsigned short* Ap = Aspec + (size_t)b * 16384 + kt * 32 + q * 8;
        #pragma unroll
        for (int mf = 0; mf < 4; ++mf) {
            bf16x8 a = *(const bf16x8*)(Ap + (size_t)(obase + mf * 16 + l15) * 128);
            acc[mf][0] = MFMA16(a, bb[0], acc[mf][0]);
            acc[mf][1] = MFMA16(a, bb[1], acc[mf][1]);
        }
    }
    __syncthreads();
    // ---- conv half: B from LDS (ds_read_b128, swizzle-matched)
    #pragma unroll
    for (int kt = 0; kt < 4; ++kt) {
        bf16x8 bb[2];
        #pragma unroll
        for (int nf = 0; nf < 2; ++nf) {
            int nl = wn * 32 + nf * 16 + l15;
            int c  = kt * 4 + q;
            int swz = (nl ^ (nl >> 2)) & 15;
            bb[nf] = *(const bf16x8*)&xs[nl * 128 + ((c ^ swz) * 8)];
        }
        const unsigned short* Ap = Wcb + kt * 32 + q * 8;
        #pragma unroll
        for (int mf = 0; mf < 4; ++mf) {
            bf16x8 a = *(const bf16x8*)(Ap + (size_t)(obase + mf * 16 + l15) * 128);
            acc[mf][0] = MFMA16(a, bb[0], acc[mf][0]);
            acc[mf][1] = MFMA16(a, bb[1], acc[mf][1]);
        }
    }
    // ---- epilogue: bias + fast GELU
    #pragma unroll
    for (int mf = 0; mf < 4; ++mf)
        #pragma unroll
        for (int nf = 0; nf < 2; ++nf)
            #pragma unroll
            for (int r = 0; r < 4; ++r) {
                int o = obase + mf * 16 + q * 4 + r;
                int n = nbase + nf * 16 + l15;
                float v = acc[mf][nf][r] + bias[o];
                float u = v * v;
                float p = v * fmaf(0.0713548162f, u, 1.5957691216f);
                float e = __expf(-p);
                float g = v * __builtin_amdgcn_rcpf(1.f + e);
                out[((size_t)(b * 128 + o)) * NN + n] = g;
            }
}

extern "C" void kernel_launch(void* const* d_in, const int* in_sizes, int n_in,
                              void* d_out, int out_size, void* d_ws, size_t ws_size,
                              hipStream_t stream) {
    const float* x    = (const float*)d_in[0];  // [16][128][8192]
    const float* wsp  = (const float*)d_in[1];  // [128][128][64][2]
    const float* wc   = (const float*)d_in[2];  // [128][128]
    const float* bc   = (const float*)d_in[3];  // [128]
    float* out = (float*)d_out;

    unsigned short* T   = (unsigned short*)d_ws;            // 2 MB
    unsigned short* Tt  = T + (size_t)1048576;              // 2 MB
    unsigned short* Wcb = Tt + (size_t)1048576;             // 32 KB
    unsigned short* Asp = Wcb + 16384;                      // 512 KB
    unsigned short* Wpk = Asp + 262144;                     // 16.8 MB
    float* Cpart = (float*)(Wpk + (size_t)8388608);         // 16 MB
    unsigned short* Axh = (unsigned short*)(Cpart + (size_t)16 * 262144);  // 512 KB

    k_prep  <<<240,  256, 0, stream>>>(wc, wsp, T, Tt, Wcb, Wpk);
    k_dftmm <<<1024, 256, 0, stream>>>(x, T, Cpart);
    k_reduce<<<1024, 256, 0, stream>>>(Cpart, Axh);
    k_mixmm <<<512,  64,  0, stream>>>(Axh, Wpk, Asp);
    k_out   <<<2048, 256, 0, stream>>>(x, Tt, Asp, Wcb, bc, out);
}

// Round 5
// 188.715 us; speedup vs baseline: 1.0818x; 1.0141x over previous
//
#include <hip/hip_runtime.h>
#include <hip/hip_bf16.h>
#include <math.h>

// (B, Cin, Cout, N, modes) = (16, 128, 128, 8192, 64)
#define NB    16
#define NCIN  128
#define NCOUT 128
#define NN    8192
#define NMOD  64

typedef short bf16x8 __attribute__((ext_vector_type(8)));   // 8 bf16 = 4 VGPRs
typedef float f32x4  __attribute__((ext_vector_type(4)));   // MFMA acc

#define MFMA16(a, b, c) __builtin_amdgcn_mfma_f32_16x16x32_bf16((a), (b), (c), 0, 0, 0)

__device__ inline unsigned short f2bf_rne(float f) {        // round-to-nearest-even
    unsigned u = __float_as_uint(f);
    u += 0x7FFF + ((u >> 16) & 1);
    return (unsigned short)(u >> 16);
}
__device__ inline short f2bf_trunc(float f) {               // cheap truncation (hot path)
    return (short)(__float_as_uint(f) >> 16);
}

// ---- trig tables (split out of k_prep for rocprof attribution) --------------
// T  [128][8192]: T[2k][n]=cos, T[2k+1][n]=-sin            (fwd-DFT B-op)
// Tt [8192][128]: Tt[n][m]=T[m][n]                         (synthesis B-op)
// Region A rebalanced: 64 blocks x 32 sincos/thread (was 16 x 128).
__global__ __launch_bounds__(256) void k_trig(unsigned short* __restrict__ T,
                                              unsigned short* __restrict__ Tt) {
    const float C = 7.66990393943e-4f; // 2*pi/8192
    if (blockIdx.x < 64) {                         // region A: T rows
        int a = blockIdx.x * 256 + threadIdx.x;    // 0..16383
        int k = a >> 8, n0 = (a & 255) * 32;
        #pragma unroll
        for (int j8 = 0; j8 < 4; ++j8) {
            short c8[8], s8[8];
            #pragma unroll
            for (int j = 0; j < 8; ++j) {
                int n = n0 + j8 * 8 + j;
                int ph = (k * n) & (NN - 1);
                float sn, cs; __sincosf((float)ph * C, &sn, &cs);
                c8[j] = (short)f2bf_rne(cs);
                s8[j] = (short)f2bf_rne(-sn);
            }
            *(bf16x8*)(T + (size_t)(2 * k) * NN + n0 + j8 * 8)     = *(bf16x8*)c8;
            *(bf16x8*)(T + (size_t)(2 * k + 1) * NN + n0 + j8 * 8) = *(bf16x8*)s8;
        }
    } else {                                       // region B: Tt rows (32 blocks)
        int n = (blockIdx.x - 64) * 256 + threadIdx.x;
        for (int k4 = 0; k4 < 16; ++k4) {
            short buf[8];
            #pragma unroll
            for (int j = 0; j < 4; ++j) {
                int k = k4 * 4 + j;
                int ph = (n * k) & (NN - 1);
                float sn, cs; __sincosf((float)ph * C, &sn, &cs);
                buf[2 * j]     = (short)f2bf_rne(cs);
                buf[2 * j + 1] = (short)f2bf_rne(-sn);
            }
            *(bf16x8*)(Tt + (size_t)n * 128 + k4 * 8) = *(bf16x8*)buf;
        }
    }
}

// ---- weight packing (split out of k_prep) -----------------------------------
// Wpk[k][h][o][kk=256] bf16: h=0 re-mix, h=1 im-mix; scale 2/N (1/N, im=0 at k=0)
// Region D: one block per o, coalesced wsp reads staged in 64KB LDS.
__global__ __launch_bounds__(256) void k_wpk(const float* __restrict__ wc,
                                             const float* __restrict__ wsp,
                                             unsigned short* __restrict__ Wcb,
                                             unsigned short* __restrict__ Wpk) {
    if (blockIdx.x < 128) {                        // region D: pack Wpk (block = o)
        int o = blockIdx.x;
        __shared__ float2 wl[8192];                // [i=128][k=64] = 64 KB
        {
            int i = threadIdx.x >> 1, h2 = threadIdx.x & 1;   // 32 float2 per thread
            const float2* src = (const float2*)wsp + (size_t)(i * 128 + o) * 64 + h2 * 32;
            float2* dst = wl + i * 64 + h2 * 32;
            #pragma unroll
            for (int j = 0; j < 32; j += 4) {      // 256B contiguous stream per thread
                float4 v0 = *(const float4*)(src + j);
                float4 v1 = *(const float4*)(src + j + 2);
                *(float4*)(dst + j)     = v0;
                *(float4*)(dst + j + 2) = v1;
            }
        }
        __syncthreads();
        int k = threadIdx.x >> 2, qc = threadIdx.x & 3;       // kk-quarter qc*64..+64
        const float s = (k == 0) ? (1.f / NN) : (2.f / NN);
        unsigned short* wre = Wpk + ((size_t)(k * 2 + 0) * 128 + o) * 256 + qc * 64;
        unsigned short* wim = wre + 32768;                    // h-stride 128*256
        #pragma unroll
        for (int c8 = 0; c8 < 4; ++c8) {           // 8 i (=16 kk) per chunk
            short re16[16], im16[16];
            #pragma unroll
            for (int t = 0; t < 8; ++t) {
                int i = qc * 32 + c8 * 8 + t;
                float2 wv = wl[i * 64 + k];
                float wr = s * wv.x, wi = s * wv.y;
                re16[2 * t]     = (short)f2bf_rne(wr);
                re16[2 * t + 1] = (short)f2bf_rne(-wi);
                im16[2 * t]     = (k == 0) ? (short)0 : (short)f2bf_rne(wi);
                im16[2 * t + 1] = (k == 0) ? (short)0 : (short)f2bf_rne(wr);
            }
            *(bf16x8*)(wre + c8 * 16)     = *(bf16x8*)re16;
            *(bf16x8*)(wre + c8 * 16 + 8) = *(bf16x8*)(re16 + 8);
            *(bf16x8*)(wim + c8 * 16)     = *(bf16x8*)im16;
            *(bf16x8*)(wim + c8 * 16 + 8) = *(bf16x8*)(im16 + 8);
        }
    } else {                                       // region C: Wc -> bf16 (64 blocks)
        int j = (blockIdx.x - 128) * 256 + threadIdx.x;
        if (j < NCOUT * NCIN) Wcb[j] = f2bf_rne(wc[j]);
    }
}

// ---- GEMM1: Cpart[sp][col][row] = (x * T^T) K-split partials ----------------
// m64 tile on the LDS-staged 2-phase pipeline: 512 blocks (32 mt x 16 sp),
// 32 KB LDS dbuf ([64 rows][128 k] bf16, XOR-swizzled), acc[4][2]/thread.
// Per c-chunk per wave: 32 MFMA : 8 T-loads (m32 was 16:8) — 2x compute
// per scattered global load; ds_reads double but are conflict-free.
__global__ __launch_bounds__(256) void k_dftmm(const float* __restrict__ x,
                                               const unsigned short* __restrict__ T,
                                               float* __restrict__ Cpart) {
    const int mt = blockIdx.x & 31, sp = blockIdx.x >> 5;
    const int w = threadIdx.x >> 6, l = threadIdx.x & 63;
    const int l15 = l & 15, q = l >> 4;
    const int colbase = w * 32;
    __shared__ short As[16384];                // 2 bufs x [64 rows][128 k] bf16, swizzled

    // staging: thread -> (row sr, 32-float group sc); 4 swizzled 16B chunks
    const int sr = threadIdx.x >> 2;           // 0..63
    const int sc = threadIdx.x & 3;            // 0..3  (floats sc*32 .. sc*32+31)
    const float* xrow = x + (size_t)(mt * 64 + sr) * NN + sp * 512 + sc * 32;
    short* wbase = As + sr * 128;

    float4 r0_, r1_, r2_, r3_, r4_, r5_, r6_, r7_;
#define LOADC(c) { const float* p_ = xrow + (c) * 128;                          \
        r0_ = *(const float4*)p_;        r1_ = *(const float4*)(p_ + 4);        \
        r2_ = *(const float4*)(p_ + 8);  r3_ = *(const float4*)(p_ + 12);       \
        r4_ = *(const float4*)(p_ + 16); r5_ = *(const float4*)(p_ + 20);       \
        r6_ = *(const float4*)(p_ + 24); r7_ = *(const float4*)(p_ + 28); }
#define PACK2(dst, u, v) { short t_[8] = {                                      \
        f2bf_trunc(u.x), f2bf_trunc(u.y), f2bf_trunc(u.z), f2bf_trunc(u.w),     \
        f2bf_trunc(v.x), f2bf_trunc(v.y), f2bf_trunc(v.z), f2bf_trunc(v.w) };   \
        *(bf16x8*)(dst) = *(bf16x8*)t_; }
#define WRITEC(bufi) {                                                          \
        PACK2(wbase + (bufi)*8192 + (((sc*4+0) ^ (sr&7))*8), r0_, r1_);         \
        PACK2(wbase + (bufi)*8192 + (((sc*4+1) ^ (sr&7))*8), r2_, r3_);         \
        PACK2(wbase + (bufi)*8192 + (((sc*4+2) ^ (sr&7))*8), r4_, r5_);         \
        PACK2(wbase + (bufi)*8192 + (((sc*4+3) ^ (sr&7))*8), r6_, r7_); }

    // B-operand bases (direct global; T slice is L2-resident across mt blocks)
    const unsigned short* Tp0 = T + (size_t)(colbase + l15) * NN + sp * 512 + q * 8;
    const unsigned short* Tp1 = Tp0 + (size_t)16 * NN;

    // A-frag reads (swizzle-matched): rows {0,16,32,48}+l15 share (row&7)=l15&7
    const int rsw = l15 & 7;

    LOADC(0);
    WRITEC(0);
    __syncthreads();

    f32x4 acc[4][2] = {};
    int buf = 0;
    for (int c = 0; c < 4; ++c) {
        if (c < 3) LOADC(c + 1);               // issue next-chunk loads early
        const short* Ab = As + buf * 8192;
        #pragma unroll
        for (int kk = 0; kk < 4; ++kk) {
            int ce = ((kk * 4 + q) ^ rsw) * 8;
            bf16x8 b0 = *(const bf16x8*)(Tp0 + c * 128 + kk * 32);
            bf16x8 b1 = *(const bf16x8*)(Tp1 + c * 128 + kk * 32);
            #pragma unroll
            for (int mf = 0; mf < 4; ++mf) {
                bf16x8 a = *(const bf16x8*)(Ab + (mf * 16 + l15) * 128 + ce);
                acc[mf][0] = MFMA16(a, b0, acc[mf][0]);
                acc[mf][1] = MFMA16(a, b1, acc[mf][1]);
            }
        }
        if (c < 3) {
            WRITEC(buf ^ 1);                   // cvt + LDS write after compute
            __syncthreads();
            buf ^= 1;
        }
    }
#undef LOADC
#undef PACK2
#undef WRITEC

    #pragma unroll
    for (int mf = 0; mf < 4; ++mf)
        #pragma unroll
        for (int nf = 0; nf < 2; ++nf) {
            int col  = colbase + nf * 16 + l15;
            int row0 = mt * 64 + mf * 16 + q * 4;
            *(f32x4*)(Cpart + (size_t)sp * 262144 + (size_t)col * 2048 + row0) = acc[mf][nf];
        }
}

// ---- reduce 16 K-split partials + cvt + permute -> Axh[k][b][2i+p] bf16 -----
// Axh is exactly k_mixmm's A-fragment layout. 2B scattered writes absorbed
// by L2 (Axh = 512 KB, resident). Decode: t = col*2048 + row ([col][row]).
__global__ __launch_bounds__(256) void k_reduce(const float* __restrict__ Cpart,
                                                unsigned short* __restrict__ Axh) {
    int t = blockIdx.x * 256 + threadIdx.x;   // 262144
    float s = 0.f;
    #pragma unroll
    for (int sp = 0; sp < 16; ++sp) s += Cpart[(size_t)sp * 262144 + t];
    int col = t >> 11, row = t & 2047;
    int k = col >> 1, p = col & 1;            // col = 2k + p
    int b = row >> 7, i = row & 127;          // row = b*128 + i
    Axh[((size_t)k * 16 + b) * 256 + i * 2 + p] = f2bf_rne(s);
}

// ---- mix: MFMA complex channel mix -> Aspec[b][o][kk=2k+p] bf16 -------------
// grid 512 blocks x 1 wave: block = (k, o-sixteenth). A-loads per-lane
// contiguous bf16x8 from Axh (no cvt).
__global__ __launch_bounds__(64) void k_mixmm(const unsigned short* __restrict__ Axh,
                                              const unsigned short* __restrict__ Wpk,
                                              unsigned short* __restrict__ Aspec) {
    const int k = blockIdx.x >> 3, oq = blockIdx.x & 7;
    const int l = threadIdx.x, l15 = l & 15, q = l >> 4;
    f32x4 ar = {}, ai = {};
    const unsigned short* Ab = Axh + ((size_t)k * 16 + l15) * 256;   // lane = b
    const int o = oq * 16 + l15;
    #pragma unroll
    for (int kt = 0; kt < 8; ++kt) {
        bf16x8 a = *(const bf16x8*)(Ab + kt * 32 + q * 8);
        const unsigned short* wb = Wpk + ((size_t)(k * 2) * 128 + o) * 256 + kt * 32 + q * 8;
        bf16x8 bre = *(const bf16x8*)wb;
        bf16x8 bim = *(const bf16x8*)(wb + 32768);   // h-stride 128*256
        ar = MFMA16(a, bre, ar);
        ai = MFMA16(a, bim, ai);
    }
    #pragma unroll
    for (int r = 0; r < 4; ++r) {
        int b = q * 4 + r;
        unsigned v = (unsigned)f2bf_rne(ar[r]) | ((unsigned)f2bf_rne(ai[r]) << 16);
        *(unsigned*)(Aspec + ((size_t)b * 128 + o) * 128 + 2 * k) = v;
    }
}

// ---- GEMM3: out = [Aspec_b | Wcb] x [Tt^T ; x_b] + bias, GELU ---------------
// Round-2 geometry (measured 51 us): n-tile 64 -> 2048 blocks (16 b x 128 nt),
// 4 waves = 2 o-halves x 2 n-halves, acc[4][2]=32 regs/thread.
__global__ __launch_bounds__(256) void k_out(const float* __restrict__ x,
                                             const unsigned short* __restrict__ Tt,
                                             const unsigned short* __restrict__ Aspec,
                                             const unsigned short* __restrict__ Wcb,
                                             const float* __restrict__ bias,
                                             float* __restrict__ out) {
    const int b = blockIdx.x >> 7, nt = blockIdx.x & 127;
    const int w = threadIdx.x >> 6, l = threadIdx.x & 63;
    const int l15 = l & 15, q = l >> 4;
    const int wo = w >> 1, wn = w & 1;
    __shared__ short xs[8192];   // 16 KB: logical [n=64][i=128], XOR-swizzled 16B chunks

    // ---- stage x-tile: fp32 coalesced reads -> bf16 pairs, transposed writes
    const float* xb = x + (size_t)b * 128 * NN + nt * 64;
    #pragma unroll
    for (int it = 0; it < 4; ++it) {
        int unit = it * 256 + threadIdx.x;       // 1024 units
        int ipair = unit >> 4, nq = unit & 15;
        int i0 = ipair * 2;
        const float* p0 = xb + (size_t)i0 * NN + nq * 4;
        float4 r0 = *(const float4*)p0;
        float4 r1 = *(const float4*)(p0 + NN);
        float a0[4] = { r0.x, r0.y, r0.z, r0.w };
        float a1[4] = { r1.x, r1.y, r1.z, r1.w };
        #pragma unroll
        for (int j = 0; j < 4; ++j) {
            int n = nq * 4 + j;
            unsigned v = (unsigned)(unsigned short)f2bf_trunc(a0[j])
                       | ((unsigned)(unsigned short)f2bf_trunc(a1[j]) << 16);
            int swz = (n ^ (n >> 2)) & 15;
            int addr = n * 128 + (((i0 >> 3) ^ swz) * 8) + (i0 & 7);
            *(unsigned*)&xs[addr] = v;
        }
    }

    const int obase = wo * 64;
    const int nbase = nt * 64 + wn * 32;
    f32x4 acc[4][2] = {};
    // ---- spectral half first (no LDS dependency -> staging drains for free)
    #pragma unroll
    for (int kt = 0; kt < 4; ++kt) {
        bf16x8 bb[2];
        #pragma unroll
        for (int nf = 0; nf < 2; ++nf) {
            int n = nbase + nf * 16 + l15;
            bb[nf] = *(const bf16x8*)(Tt + (size_t)n * 128 + kt * 32 + q * 8);
        }
        const unsigned short* Ap = Aspec + (size_t)b * 16384 + kt * 32 + q * 8;
        #pragma unroll
        for (int mf = 0; mf < 4; ++mf) {
            bf16x8 a = *(const bf16x8*)(Ap + (size_t)(obase + mf * 16 + l15) * 128);
            acc[mf][0] = MFMA16(a, bb[0], acc[mf][0]);
            acc[mf][1] = MFMA16(a, bb[1], acc[mf][1]);
        }
    }
    __syncthreads();
    // ---- conv half: B from LDS (ds_read_b128, swizzle-matched)
    #pragma unroll
    for (int kt = 0; kt < 4; ++kt) {
        bf16x8 bb[2];
        #pragma unroll
        for (int nf = 0; nf < 2; ++nf) {
            int nl = wn * 32 + nf * 16 + l15;
            int c  = kt * 4 + q;
            int swz = (nl ^ (nl >> 2)) & 15;
            bb[nf] = *(const bf16x8*)&xs[nl * 128 + ((c ^ swz) * 8)];
        }
        const unsigned short* Ap = Wcb + kt * 32 + q * 8;
        #pragma unroll
        for (int mf = 0; mf < 4; ++mf) {
            bf16x8 a = *(const bf16x8*)(Ap + (size_t)(obase + mf * 16 + l15) * 128);
            acc[mf][0] = MFMA16(a, bb[0], acc[mf][0]);
            acc[mf][1] = MFMA16(a, bb[1], acc[mf][1]);
        }
    }
    // ---- epilogue: bias + fast GELU
    #pragma unroll
    for (int mf = 0; mf < 4; ++mf)
        #pragma unroll
        for (int nf = 0; nf < 2; ++nf)
            #pragma unroll
            for (int r = 0; r < 4; ++r) {
                int o = obase + mf * 16 + q * 4 + r;
                int n = nbase + nf * 16 + l15;
                float v = acc[mf][nf][r] + bias[o];
                float u = v * v;
                float p = v * fmaf(0.0713548162f, u, 1.5957691216f);
                float e = __expf(-p);
                float g = v * __builtin_amdgcn_rcpf(1.f + e);
                out[((size_t)(b * 128 + o)) * NN + n] = g;
            }
}

extern "C" void kernel_launch(void* const* d_in, const int* in_sizes, int n_in,
                              void* d_out, int out_size, void* d_ws, size_t ws_size,
                              hipStream_t stream) {
    const float* x    = (const float*)d_in[0];  // [16][128][8192]
    const float* wsp  = (const float*)d_in[1];  // [128][128][64][2]
    const float* wc   = (const float*)d_in[2];  // [128][128]
    const float* bc   = (const float*)d_in[3];  // [128]
    float* out = (float*)d_out;

    unsigned short* T   = (unsigned short*)d_ws;            // 2 MB
    unsigned short* Tt  = T + (size_t)1048576;              // 2 MB
    unsigned short* Wcb = Tt + (size_t)1048576;             // 32 KB
    unsigned short* Asp = Wcb + 16384;                      // 512 KB
    unsigned short* Wpk = Asp + 262144;                     // 16.8 MB
    float* Cpart = (float*)(Wpk + (size_t)8388608);         // 16 MB
    unsigned short* Axh = (unsigned short*)(Cpart + (size_t)16 * 262144);  // 512 KB

    k_trig  <<<96,   256, 0, stream>>>(T, Tt);
    k_wpk   <<<192,  256, 0, stream>>>(wc, wsp, Wcb, Wpk);
    k_dftmm <<<512,  256, 0, stream>>>(x, T, Cpart);
    k_reduce<<<1024, 256, 0, stream>>>(Cpart, Axh);
    k_mixmm <<<512,  64,  0, stream>>>(Axh, Wpk, Asp);
    k_out   <<<2048, 256, 0, stream>>>(x, Tt, Asp, Wcb, bc, out);
}

// Round 6
// 186.899 us; speedup vs baseline: 1.0923x; 1.0097x over previous
//
#include <hip/hip_runtime.h>
#include <hip/hip_bf16.h>
#include <math.h>

// (B, Cin, Cout, N, modes) = (16, 128, 128, 8192, 64)
#define NB    16
#define NCIN  128
#define NCOUT 128
#define NN    8192
#define NMOD  64

typedef short bf16x8 __attribute__((ext_vector_type(8)));   // 8 bf16 = 4 VGPRs
typedef float f32x4  __attribute__((ext_vector_type(4)));   // MFMA acc

#define MFMA16(a, b, c) __builtin_amdgcn_mfma_f32_16x16x32_bf16((a), (b), (c), 0, 0, 0)

__device__ inline unsigned short f2bf_rne(float f) {        // round-to-nearest-even
    unsigned u = __float_as_uint(f);
    u += 0x7FFF + ((u >> 16) & 1);
    return (unsigned short)(u >> 16);
}
__device__ inline short f2bf_trunc(float f) {               // cheap truncation (hot path)
    return (short)(__float_as_uint(f) >> 16);
}

// ---- prep (ONE launch, 256 blocks; regions run concurrently) ----------------
// T  [128][8192]: T[2k][n]=cos, T[2k+1][n]=-sin            (fwd-DFT B-op)
// Tt [8192][128]: Tt[n][m]=T[m][n]                         (synthesis B-op)
// Wpk[k][h][o][kk=256] bf16: h=0 re-mix, h=1 im-mix; scale 2/N (1/N, im=0 at k=0)
// Trig via complex-rotation recurrence: 1-2 sincos/thread + 4-FMA steps
// (error ~63*eps ~ 1e-5 << bf16 quantum; was ~2M sincos total).
__global__ __launch_bounds__(256) void k_prep(const float* __restrict__ wc,
                                              const float* __restrict__ wsp,
                                              unsigned short* __restrict__ T,
                                              unsigned short* __restrict__ Tt,
                                              unsigned short* __restrict__ Wcb,
                                              unsigned short* __restrict__ Wpk) {
    const float C = 7.66990393943e-4f; // 2*pi/8192
    if (blockIdx.x < 128) {                        // region D: pack Wpk (block = o)
        int o = blockIdx.x;
        __shared__ float2 wl[8192];                // [i=128][k=64] = 64 KB
        {
            int i = threadIdx.x >> 1, h2 = threadIdx.x & 1;   // 32 float2 per thread
            const float2* src = (const float2*)wsp + (size_t)(i * 128 + o) * 64 + h2 * 32;
            float2* dst = wl + i * 64 + h2 * 32;
            #pragma unroll
            for (int j = 0; j < 32; j += 4) {      // 256B contiguous stream per thread
                float4 v0 = *(const float4*)(src + j);
                float4 v1 = *(const float4*)(src + j + 2);
                *(float4*)(dst + j)     = v0;
                *(float4*)(dst + j + 2) = v1;
            }
        }
        __syncthreads();
        int k = threadIdx.x >> 2, qc = threadIdx.x & 3;       // kk-quarter qc*64..+64
        const float s = (k == 0) ? (1.f / NN) : (2.f / NN);
        unsigned short* wre = Wpk + ((size_t)(k * 2 + 0) * 128 + o) * 256 + qc * 64;
        unsigned short* wim = wre + 32768;                    // h-stride 128*256
        #pragma unroll
        for (int c8 = 0; c8 < 4; ++c8) {           // 8 i (=16 kk) per chunk
            short re16[16], im16[16];
            #pragma unroll
            for (int t = 0; t < 8; ++t) {
                int i = qc * 32 + c8 * 8 + t;
                float2 wv = wl[i * 64 + k];
                float wr = s * wv.x, wi = s * wv.y;
                re16[2 * t]     = (short)f2bf_rne(wr);
                re16[2 * t + 1] = (short)f2bf_rne(-wi);
                im16[2 * t]     = (k == 0) ? (short)0 : (short)f2bf_rne(wi);
                im16[2 * t + 1] = (k == 0) ? (short)0 : (short)f2bf_rne(wr);
            }
            *(bf16x8*)(wre + c8 * 16)     = *(bf16x8*)re16;
            *(bf16x8*)(wre + c8 * 16 + 8) = *(bf16x8*)(re16 + 8);
            *(bf16x8*)(wim + c8 * 16)     = *(bf16x8*)im16;
            *(bf16x8*)(wim + c8 * 16 + 8) = *(bf16x8*)(im16 + 8);
        }
    } else if (blockIdx.x < 192) {                 // region A: T rows (64 blocks)
        int a = (blockIdx.x - 128) * 256 + threadIdx.x;   // 0..16383
        int k = a >> 7, n0 = (a & 127) * 64;       // 64 n per thread
        float cv, sv, dc, ds;
        __sincosf((float)((k * n0) & (NN - 1)) * C, &sv, &cv);
        __sincosf((float)k * C, &ds, &dc);         // per-n rotation step
        #pragma unroll
        for (int j8 = 0; j8 < 8; ++j8) {
            short c8[8], s8[8];
            #pragma unroll
            for (int j = 0; j < 8; ++j) {
                c8[j] = (short)f2bf_rne(cv);
                s8[j] = (short)f2bf_rne(-sv);
                float cn = cv * dc - sv * ds;
                sv = sv * dc + cv * ds;
                cv = cn;
            }
            *(bf16x8*)(T + (size_t)(2 * k) * NN + n0 + j8 * 8)     = *(bf16x8*)c8;
            *(bf16x8*)(T + (size_t)(2 * k + 1) * NN + n0 + j8 * 8) = *(bf16x8*)s8;
        }
    } else if (blockIdx.x < 224) {                 // region B: Tt rows (32 blocks)
        int n = (blockIdx.x - 192) * 256 + threadIdx.x;   // 0..8191
        float dc, ds;
        __sincosf((float)n * C, &ds, &dc);         // per-k rotation step
        float cv = 1.f, sv = 0.f;                  // k = 0
        for (int k8 = 0; k8 < 16; ++k8) {
            short buf[8];
            #pragma unroll
            for (int j = 0; j < 4; ++j) {
                buf[2 * j]     = (short)f2bf_rne(cv);
                buf[2 * j + 1] = (short)f2bf_rne(-sv);
                float cn = cv * dc - sv * ds;
                sv = sv * dc + cv * ds;
                cv = cn;
            }
            *(bf16x8*)(Tt + (size_t)n * 128 + k8 * 8) = *(bf16x8*)buf;
        }
    } else {                                       // region C: Wc -> bf16 (32 blocks)
        int g = (blockIdx.x - 224) * 256 + threadIdx.x;   // 0..8191, 2 elems each
        float2 v = *(const float2*)(wc + g * 2);
        unsigned pk = (unsigned)f2bf_rne(v.x) | ((unsigned)f2bf_rne(v.y) << 16);
        *(unsigned*)(Wcb + g * 2) = pk;
    }
}

// ---- GEMM1: Cpart[sp][col][row] = (x * T^T) K-split partials ----------------
// m64 tile on the LDS-staged 2-phase pipeline: 512 blocks (32 mt x 16 sp),
// 32 KB LDS dbuf ([64 rows][128 k] bf16, XOR-swizzled), acc[4][2]/thread.
__global__ __launch_bounds__(256) void k_dftmm(const float* __restrict__ x,
                                               const unsigned short* __restrict__ T,
                                               float* __restrict__ Cpart) {
    const int mt = blockIdx.x & 31, sp = blockIdx.x >> 5;
    const int w = threadIdx.x >> 6, l = threadIdx.x & 63;
    const int l15 = l & 15, q = l >> 4;
    const int colbase = w * 32;
    __shared__ short As[16384];                // 2 bufs x [64 rows][128 k] bf16, swizzled

    // staging: thread -> (row sr, 32-float group sc); 4 swizzled 16B chunks
    const int sr = threadIdx.x >> 2;           // 0..63
    const int sc = threadIdx.x & 3;            // 0..3  (floats sc*32 .. sc*32+31)
    const float* xrow = x + (size_t)(mt * 64 + sr) * NN + sp * 512 + sc * 32;
    short* wbase = As + sr * 128;

    float4 r0_, r1_, r2_, r3_, r4_, r5_, r6_, r7_;
#define LOADC(c) { const float* p_ = xrow + (c) * 128;                          \
        r0_ = *(const float4*)p_;        r1_ = *(const float4*)(p_ + 4);        \
        r2_ = *(const float4*)(p_ + 8);  r3_ = *(const float4*)(p_ + 12);       \
        r4_ = *(const float4*)(p_ + 16); r5_ = *(const float4*)(p_ + 20);       \
        r6_ = *(const float4*)(p_ + 24); r7_ = *(const float4*)(p_ + 28); }
#define PACK2(dst, u, v) { short t_[8] = {                                      \
        f2bf_trunc(u.x), f2bf_trunc(u.y), f2bf_trunc(u.z), f2bf_trunc(u.w),     \
        f2bf_trunc(v.x), f2bf_trunc(v.y), f2bf_trunc(v.z), f2bf_trunc(v.w) };   \
        *(bf16x8*)(dst) = *(bf16x8*)t_; }
#define WRITEC(bufi) {                                                          \
        PACK2(wbase + (bufi)*8192 + (((sc*4+0) ^ (sr&7))*8), r0_, r1_);         \
        PACK2(wbase + (bufi)*8192 + (((sc*4+1) ^ (sr&7))*8), r2_, r3_);         \
        PACK2(wbase + (bufi)*8192 + (((sc*4+2) ^ (sr&7))*8), r4_, r5_);         \
        PACK2(wbase + (bufi)*8192 + (((sc*4+3) ^ (sr&7))*8), r6_, r7_); }

    // B-operand bases (direct global; T slice is L2-resident across mt blocks)
    const unsigned short* Tp0 = T + (size_t)(colbase + l15) * NN + sp * 512 + q * 8;
    const unsigned short* Tp1 = Tp0 + (size_t)16 * NN;

    // A-frag reads (swizzle-matched): rows {0,16,32,48}+l15 share (row&7)=l15&7
    const int rsw = l15 & 7;

    LOADC(0);
    WRITEC(0);
    __syncthreads();

    f32x4 acc[4][2] = {};
    int buf = 0;
    for (int c = 0; c < 4; ++c) {
        if (c < 3) LOADC(c + 1);               // issue next-chunk loads early
        const short* Ab = As + buf * 8192;
        #pragma unroll
        for (int kk = 0; kk < 4; ++kk) {
            int ce = ((kk * 4 + q) ^ rsw) * 8;
            bf16x8 b0 = *(const bf16x8*)(Tp0 + c * 128 + kk * 32);
            bf16x8 b1 = *(const bf16x8*)(Tp1 + c * 128 + kk * 32);
            #pragma unroll
            for (int mf = 0; mf < 4; ++mf) {
                bf16x8 a = *(const bf16x8*)(Ab + (mf * 16 + l15) * 128 + ce);
                acc[mf][0] = MFMA16(a, b0, acc[mf][0]);
                acc[mf][1] = MFMA16(a, b1, acc[mf][1]);
            }
        }
        if (c < 3) {
            WRITEC(buf ^ 1);                   // cvt + LDS write after compute
            __syncthreads();
            buf ^= 1;
        }
    }
#undef LOADC
#undef PACK2
#undef WRITEC

    #pragma unroll
    for (int mf = 0; mf < 4; ++mf)
        #pragma unroll
        for (int nf = 0; nf < 2; ++nf) {
            int col  = colbase + nf * 16 + l15;
            int row0 = mt * 64 + mf * 16 + q * 4;
            *(f32x4*)(Cpart + (size_t)sp * 262144 + (size_t)col * 2048 + row0) = acc[mf][nf];
        }
}

// ---- reduce 16 K-split partials + cvt + permute -> Axh[k][b][2i+p] bf16 -----
// Axh is exactly k_mixmm's A-fragment layout. 2B scattered writes absorbed
// by L2 (Axh = 512 KB, resident). Decode: t = col*2048 + row ([col][row]).
__global__ __launch_bounds__(256) void k_reduce(const float* __restrict__ Cpart,
                                                unsigned short* __restrict__ Axh) {
    int t = blockIdx.x * 256 + threadIdx.x;   // 262144
    float s = 0.f;
    #pragma unroll
    for (int sp = 0; sp < 16; ++sp) s += Cpart[(size_t)sp * 262144 + t];
    int col = t >> 11, row = t & 2047;
    int k = col >> 1, p = col & 1;            // col = 2k + p
    int b = row >> 7, i = row & 127;          // row = b*128 + i
    Axh[((size_t)k * 16 + b) * 256 + i * 2 + p] = f2bf_rne(s);
}

// ---- mix: MFMA complex channel mix -> Aspec[b][o][kk=2k+p] bf16 -------------
// grid 512 blocks x 1 wave: block = (k, o-sixteenth). A-loads per-lane
// contiguous bf16x8 from Axh (no cvt).
__global__ __launch_bounds__(64) void k_mixmm(const unsigned short* __restrict__ Axh,
                                              const unsigned short* __restrict__ Wpk,
                                              unsigned short* __restrict__ Aspec) {
    const int k = blockIdx.x >> 3, oq = blockIdx.x & 7;
    const int l = threadIdx.x, l15 = l & 15, q = l >> 4;
    f32x4 ar = {}, ai = {};
    const unsigned short* Ab = Axh + ((size_t)k * 16 + l15) * 256;   // lane = b
    const int o = oq * 16 + l15;
    #pragma unroll
    for (int kt = 0; kt < 8; ++kt) {
        bf16x8 a = *(const bf16x8*)(Ab + kt * 32 + q * 8);
        const unsigned short* wb = Wpk + ((size_t)(k * 2) * 128 + o) * 256 + kt * 32 + q * 8;
        bf16x8 bre = *(const bf16x8*)wb;
        bf16x8 bim = *(const bf16x8*)(wb + 32768);   // h-stride 128*256
        ar = MFMA16(a, bre, ar);
        ai = MFMA16(a, bim, ai);
    }
    #pragma unroll
    for (int r = 0; r < 4; ++r) {
        int b = q * 4 + r;
        unsigned v = (unsigned)f2bf_rne(ar[r]) | ((unsigned)f2bf_rne(ai[r]) << 16);
        *(unsigned*)(Aspec + ((size_t)b * 128 + o) * 128 + 2 * k) = v;
    }
}

// ---- GEMM3: out = [Aspec_b | Wcb] x [Tt^T ; x_b] + bias, GELU ---------------
// Verified geometry (51 us): n-tile 64 -> 2048 blocks (16 b x 128 nt),
// 4 waves = 2 o-halves x 2 n-halves, acc[4][2]=32 regs/thread.
// (n32 and o-splits both regress via operand replication — measured r3.)
__global__ __launch_bounds__(256) void k_out(const float* __restrict__ x,
                                             const unsigned short* __restrict__ Tt,
                                             const unsigned short* __restrict__ Aspec,
                                             const unsigned short* __restrict__ Wcb,
                                             const float* __restrict__ bias,
                                             float* __restrict__ out) {
    const int b = blockIdx.x >> 7, nt = blockIdx.x & 127;
    const int w = threadIdx.x >> 6, l = threadIdx.x & 63;
    const int l15 = l & 15, q = l >> 4;
    const int wo = w >> 1, wn = w & 1;
    __shared__ short xs[8192];   // 16 KB: logical [n=64][i=128], XOR-swizzled 16B chunks

    // ---- stage x-tile: fp32 coalesced reads -> bf16 pairs, transposed writes
    const float* xb = x + (size_t)b * 128 * NN + nt * 64;
    #pragma unroll
    for (int it = 0; it < 4; ++it) {
        int unit = it * 256 + threadIdx.x;       // 1024 units
        int ipair = unit >> 4, nq = unit & 15;
        int i0 = ipair * 2;
        const float* p0 = xb + (size_t)i0 * NN + nq * 4;
        float4 r0 = *(const float4*)p0;
        float4 r1 = *(const float4*)(p0 + NN);
        float a0[4] = { r0.x, r0.y, r0.z, r0.w };
        float a1[4] = { r1.x, r1.y, r1.z, r1.w };
        #pragma unroll
        for (int j = 0; j < 4; ++j) {
            int n = nq * 4 + j;
            unsigned v = (unsigned)(unsigned short)f2bf_trunc(a0[j])
                       | ((unsigned)(unsigned short)f2bf_trunc(a1[j]) << 16);
            int swz = (n ^ (n >> 2)) & 15;
            int addr = n * 128 + (((i0 >> 3) ^ swz) * 8) + (i0 & 7);
            *(unsigned*)&xs[addr] = v;
        }
    }

    const int obase = wo * 64;
    const int nbase = nt * 64 + wn * 32;
    f32x4 acc[4][2] = {};
    // ---- spectral half first (no LDS dependency -> staging drains for free)
    #pragma unroll
    for (int kt = 0; kt < 4; ++kt) {
        bf16x8 bb[2];
        #pragma unroll
        for (int nf = 0; nf < 2; ++nf) {
            int n = nbase + nf * 16 + l15;
            bb[nf] = *(const bf16x8*)(Tt + (size_t)n * 128 + kt * 32 + q * 8);
        }
        const unsigned short* Ap = Aspec + (size_t)b * 16384 + kt * 32 + q * 8;
        #pragma unroll
        for (int mf = 0; mf < 4; ++mf) {
            bf16x8 a = *(const bf16x8*)(Ap + (size_t)(obase + mf * 16 + l15) * 128);
            acc[mf][0] = MFMA16(a, bb[0], acc[mf][0]);
            acc[mf][1] = MFMA16(a, bb[1], acc[mf][1]);
        }
    }
    __syncthreads();
    // ---- conv half: B from LDS (ds_read_b128, swizzle-matched)
    #pragma unroll
    for (int kt = 0; kt < 4; ++kt) {
        bf16x8 bb[2];
        #pragma unroll
        for (int nf = 0; nf < 2; ++nf) {
            int nl = wn * 32 + nf * 16 + l15;
            int c  = kt * 4 + q;
            int swz = (nl ^ (nl >> 2)) & 15;
            bb[nf] = *(const bf16x8*)&xs[nl * 128 + ((c ^ swz) * 8)];
        }
        const unsigned short* Ap = Wcb + kt * 32 + q * 8;
        #pragma unroll
        for (int mf = 0; mf < 4; ++mf) {
            bf16x8 a = *(const bf16x8*)(Ap + (size_t)(obase + mf * 16 + l15) * 128);
            acc[mf][0] = MFMA16(a, bb[0], acc[mf][0]);
            acc[mf][1] = MFMA16(a, bb[1], acc[mf][1]);
        }
    }
    // ---- epilogue: bias + fast GELU
    #pragma unroll
    for (int mf = 0; mf < 4; ++mf)
        #pragma unroll
        for (int nf = 0; nf < 2; ++nf)
            #pragma unroll
            for (int r = 0; r < 4; ++r) {
                int o = obase + mf * 16 + q * 4 + r;
                int n = nbase + nf * 16 + l15;
                float v = acc[mf][nf][r] + bias[o];
                float u = v * v;
                float p = v * fmaf(0.0713548162f, u, 1.5957691216f);
                float e = __expf(-p);
                float g = v * __builtin_amdgcn_rcpf(1.f + e);
                out[((size_t)(b * 128 + o)) * NN + n] = g;
            }
}

extern "C" void kernel_launch(void* const* d_in, const int* in_sizes, int n_in,
                              void* d_out, int out_size, void* d_ws, size_t ws_size,
                              hipStream_t stream) {
    const float* x    = (const float*)d_in[0];  // [16][128][8192]
    const float* wsp  = (const float*)d_in[1];  // [128][128][64][2]
    const float* wc   = (const float*)d_in[2];  // [128][128]
    const float* bc   = (const float*)d_in[3];  // [128]
    float* out = (float*)d_out;

    unsigned short* T   = (unsigned short*)d_ws;            // 2 MB
    unsigned short* Tt  = T + (size_t)1048576;              // 2 MB
    unsigned short* Wcb = Tt + (size_t)1048576;             // 32 KB
    unsigned short* Asp = Wcb + 16384;                      // 512 KB
    unsigned short* Wpk = Asp + 262144;                     // 16.8 MB
    float* Cpart = (float*)(Wpk + (size_t)8388608);         // 16 MB
    unsigned short* Axh = (unsigned short*)(Cpart + (size_t)16 * 262144);  // 512 KB

    k_prep  <<<256,  256, 0, stream>>>(wc, wsp, T, Tt, Wcb, Wpk);
    k_dftmm <<<512,  256, 0, stream>>>(x, T, Cpart);
    k_reduce<<<1024, 256, 0, stream>>>(Cpart, Axh);
    k_mixmm <<<512,  64,  0, stream>>>(Axh, Wpk, Asp);
    k_out   <<<2048, 256, 0, stream>>>(x, Tt, Asp, Wcb, bc, out);
}